// Round 1
// baseline (2709.066 us; speedup 1.0000x reference)
//
#include <hip/hip_runtime.h>
#include <cmath>

// LAGCNII: h0 = concat(relu(x0@W0+b0), relu(x1@W1+b1));
// 8x { x = 0.9*segsum(h[src]->dst) + 0.1*h0 ; h = relu((1-b)x + b*(x@Wl)) };
// out = h@Wo + bo.
// Round 0: fp32 VALU tiled GEMMs + CSR gather aggregation (no atomics in hot path).
// ws layout: h0 | h | x (3 x 102.4MB) + cnt/rowp/fill/col (~2.4MB) ~= 310MB.

#define N_NODES 100000
#define N_EDGES 300000
#define DIN 256
#define CHN 256
#define DHID 128
#define NCLASS 40
#define NLAYER 8

// ---------------- CSR build (by dst) ----------------
__global__ void hist_kernel(const int* __restrict__ dst, int* __restrict__ cnt) {
  int e = blockIdx.x * 256 + threadIdx.x;
  if (e < N_EDGES) atomicAdd(&cnt[dst[e]], 1);
}

__global__ __launch_bounds__(1024) void scan_kernel(const int* __restrict__ cnt,
                                                    int* __restrict__ rowp,
                                                    int* __restrict__ fill) {
  __shared__ int buf[1024];
  __shared__ int carry;
  int tid = threadIdx.x;
  if (tid == 0) carry = 0;
  __syncthreads();
  for (int base = 0; base < N_NODES; base += 1024) {
    int i = base + tid;
    int v = (i < N_NODES) ? cnt[i] : 0;
    buf[tid] = v;
    __syncthreads();
    for (int off = 1; off < 1024; off <<= 1) {
      int t = (tid >= off) ? buf[tid - off] : 0;
      __syncthreads();
      buf[tid] += t;
      __syncthreads();
    }
    int excl = buf[tid] - v;
    if (i < N_NODES) { int p = carry + excl; rowp[i] = p; fill[i] = p; }
    __syncthreads();
    if (tid == 1023) carry += buf[1023];
    __syncthreads();
  }
  if (tid == 0) rowp[N_NODES] = carry;
}

__global__ void scatter_kernel(const int* __restrict__ src, const int* __restrict__ dst,
                               int* __restrict__ fill, int* __restrict__ col) {
  int e = blockIdx.x * 256 + threadIdx.x;
  if (e < N_EDGES) {
    int p = atomicAdd(&fill[dst[e]], 1);
    col[p] = src[e];
  }
}

// ---------------- lin: h0[:,v*128:(v+1)*128] = relu(xv @ Wv + bv) ----------------
// tile 64 rows x 128 cols, block 256, micro 4x8, K-chunk 16
__global__ __launch_bounds__(256) void lin_kernel(const float* __restrict__ x0,
                                                  const float* __restrict__ x1,
                                                  const float* __restrict__ lw,
                                                  const float* __restrict__ lb,
                                                  float* __restrict__ h0) {
  const int view = blockIdx.y;
  const float* __restrict__ X = view ? x1 : x0;
  const float* __restrict__ W = lw + view * (DIN * DHID);
  const int row0 = blockIdx.x * 64;
  __shared__ float AT[16][68];   // [k][m], padded (68*4 % 16 == 0)
  __shared__ float BS[16][128];  // [k][n]
  const int tid = threadIdx.x;
  const int ty = tid >> 4, tx = tid & 15;
  float acc[4][8];
#pragma unroll
  for (int i = 0; i < 4; i++)
#pragma unroll
    for (int j = 0; j < 8; j++) acc[i][j] = 0.f;

  const int lr = tid >> 2;
  const int lk = (tid & 3) * 4;
  for (int k0 = 0; k0 < DIN; k0 += 16) {
    int gr = row0 + lr;
    float4 av = make_float4(0.f, 0.f, 0.f, 0.f);
    if (gr < N_NODES) av = *(const float4*)(X + (size_t)gr * DIN + k0 + lk);
    AT[lk + 0][lr] = av.x; AT[lk + 1][lr] = av.y;
    AT[lk + 2][lr] = av.z; AT[lk + 3][lr] = av.w;
    {
      int f = tid * 2;
      int k = f >> 5;
      int n = (f & 31) * 4;
      const float* wp = W + (size_t)(k0 + k) * DHID + n;
      float4 v0 = *(const float4*)wp;
      float4 v1 = *(const float4*)(wp + 4);
      *(float4*)&BS[k][n] = v0;
      *(float4*)&BS[k][n + 4] = v1;
    }
    __syncthreads();
#pragma unroll
    for (int kk = 0; kk < 16; kk++) {
      float a[4], b[8];
      *(float4*)a = *(const float4*)&AT[kk][ty * 4];
      *(float4*)(b) = *(const float4*)&BS[kk][tx * 8];
      *(float4*)(b + 4) = *(const float4*)&BS[kk][tx * 8 + 4];
#pragma unroll
      for (int i = 0; i < 4; i++)
#pragma unroll
        for (int j = 0; j < 8; j++) acc[i][j] += a[i] * b[j];
    }
    __syncthreads();
  }
#pragma unroll
  for (int i = 0; i < 4; i++) {
    int gr = row0 + ty * 4 + i;
    if (gr >= N_NODES) continue;
    float bb[8];
#pragma unroll
    for (int j = 0; j < 8; j++) bb[j] = lb[view * DHID + tx * 8 + j];
    float4 o0, o1;
    o0.x = fmaxf(acc[i][0] + bb[0], 0.f);
    o0.y = fmaxf(acc[i][1] + bb[1], 0.f);
    o0.z = fmaxf(acc[i][2] + bb[2], 0.f);
    o0.w = fmaxf(acc[i][3] + bb[3], 0.f);
    o1.x = fmaxf(acc[i][4] + bb[4], 0.f);
    o1.y = fmaxf(acc[i][5] + bb[5], 0.f);
    o1.z = fmaxf(acc[i][6] + bb[6], 0.f);
    o1.w = fmaxf(acc[i][7] + bb[7], 0.f);
    float* op = h0 + (size_t)gr * CHN + view * DHID + tx * 8;
    *(float4*)op = o0;
    *(float4*)(op + 4) = o1;
  }
}

// ---------------- aggregation: x = 0.9*sum_{e: dst=n} h[src_e] + 0.1*h0[n] ----------------
// one wave per node, 4 nodes per block
__global__ __launch_bounds__(256) void agg_kernel(const float* __restrict__ h,
                                                  const float* __restrict__ h0,
                                                  const int* __restrict__ rowp,
                                                  const int* __restrict__ col,
                                                  float* __restrict__ x) {
  int node = blockIdx.x * 4 + (threadIdx.x >> 6);
  int t = threadIdx.x & 63;
  int beg = rowp[node], end = rowp[node + 1];
  float4 acc = make_float4(0.f, 0.f, 0.f, 0.f);
  for (int e = beg; e < end; ++e) {
    int s = col[e];
    float4 v = *(const float4*)(h + (size_t)s * CHN + t * 4);
    acc.x += v.x; acc.y += v.y; acc.z += v.z; acc.w += v.w;
  }
  float4 r = *(const float4*)(h0 + (size_t)node * CHN + t * 4);
  float4 o;
  o.x = 0.9f * acc.x + 0.1f * r.x;
  o.y = 0.9f * acc.y + 0.1f * r.y;
  o.z = 0.9f * acc.z + 0.1f * r.z;
  o.w = 0.9f * acc.w + 0.1f * r.w;
  *(float4*)(x + (size_t)node * CHN + t * 4) = o;
}

// ---------------- layer GEMM: h = relu((1-b)*x + b*(x@W)) ----------------
// tile 64 rows x 128 cols (gridDim.y=2 covers 256 cols), micro 4x8, K-chunk 16
__global__ __launch_bounds__(256) void layer_gemm_kernel(const float* __restrict__ x,
                                                         const float* __restrict__ W,
                                                         float* __restrict__ h,
                                                         float beta) {
  const int row0 = blockIdx.x * 64;
  const int col0 = blockIdx.y * 128;
  __shared__ float AT[16][68];
  __shared__ float BS[16][128];
  const int tid = threadIdx.x;
  const int ty = tid >> 4, tx = tid & 15;
  float acc[4][8];
#pragma unroll
  for (int i = 0; i < 4; i++)
#pragma unroll
    for (int j = 0; j < 8; j++) acc[i][j] = 0.f;

  const int lr = tid >> 2;
  const int lk = (tid & 3) * 4;
  for (int k0 = 0; k0 < CHN; k0 += 16) {
    int gr = row0 + lr;
    float4 av = make_float4(0.f, 0.f, 0.f, 0.f);
    if (gr < N_NODES) av = *(const float4*)(x + (size_t)gr * CHN + k0 + lk);
    AT[lk + 0][lr] = av.x; AT[lk + 1][lr] = av.y;
    AT[lk + 2][lr] = av.z; AT[lk + 3][lr] = av.w;
    {
      int f = tid * 2;
      int k = f >> 5;
      int n = (f & 31) * 4;
      const float* wp = W + (size_t)(k0 + k) * CHN + col0 + n;
      float4 v0 = *(const float4*)wp;
      float4 v1 = *(const float4*)(wp + 4);
      *(float4*)&BS[k][n] = v0;
      *(float4*)&BS[k][n + 4] = v1;
    }
    __syncthreads();
#pragma unroll
    for (int kk = 0; kk < 16; kk++) {
      float a[4], b[8];
      *(float4*)a = *(const float4*)&AT[kk][ty * 4];
      *(float4*)(b) = *(const float4*)&BS[kk][tx * 8];
      *(float4*)(b + 4) = *(const float4*)&BS[kk][tx * 8 + 4];
#pragma unroll
      for (int i = 0; i < 4; i++)
#pragma unroll
        for (int j = 0; j < 8; j++) acc[i][j] += a[i] * b[j];
    }
    __syncthreads();
  }
  const float omb = 1.f - beta;
#pragma unroll
  for (int i = 0; i < 4; i++) {
    int gr = row0 + ty * 4 + i;
    if (gr >= N_NODES) continue;
    const float* xp = x + (size_t)gr * CHN + col0 + tx * 8;
    float4 xv0 = *(const float4*)xp;
    float4 xv1 = *(const float4*)(xp + 4);
    float4 o0, o1;
    o0.x = fmaxf(omb * xv0.x + beta * acc[i][0], 0.f);
    o0.y = fmaxf(omb * xv0.y + beta * acc[i][1], 0.f);
    o0.z = fmaxf(omb * xv0.z + beta * acc[i][2], 0.f);
    o0.w = fmaxf(omb * xv0.w + beta * acc[i][3], 0.f);
    o1.x = fmaxf(omb * xv1.x + beta * acc[i][4], 0.f);
    o1.y = fmaxf(omb * xv1.y + beta * acc[i][5], 0.f);
    o1.z = fmaxf(omb * xv1.z + beta * acc[i][6], 0.f);
    o1.w = fmaxf(omb * xv1.w + beta * acc[i][7], 0.f);
    float* op = h + (size_t)gr * CHN + col0 + tx * 8;
    *(float4*)op = o0;
    *(float4*)(op + 4) = o1;
  }
}

// ---------------- out: out = h @ Wo + bo  (M=100000, K=256, N=40) ----------------
// block 256, 32 rows per block; x tile + W chunks in LDS
__global__ __launch_bounds__(256) void out_kernel(const float* __restrict__ h,
                                                  const float* __restrict__ W,
                                                  const float* __restrict__ b,
                                                  float* __restrict__ out) {
  __shared__ float xs[32][260];  // padded: bank = (4r + k) % 32, conflict-free
  __shared__ float ws[64][40];
  const int row0 = blockIdx.x * 32;
  const int tid = threadIdx.x;
  for (int f = tid; f < 2048; f += 256) {
    int r = f >> 6;
    int c = (f & 63) * 4;
    *(float4*)&xs[r][c] = *(const float4*)(h + (size_t)(row0 + r) * CHN + c);
  }
  const int r = tid >> 3;
  const int cg = (tid & 7) * 5;
  float acc[5];
#pragma unroll
  for (int j = 0; j < 5; j++) acc[j] = b[cg + j];
  for (int k0 = 0; k0 < CHN; k0 += 64) {
    for (int i = tid; i < 64 * 40; i += 256) {
      int k = i / 40, c = i % 40;
      ws[k][c] = W[(size_t)(k0 + k) * NCLASS + c];
    }
    __syncthreads();
#pragma unroll 8
    for (int k = 0; k < 64; k++) {
      float xv = xs[r][k0 + k];
#pragma unroll
      for (int j = 0; j < 5; j++) acc[j] += xv * ws[k][cg + j];
    }
    __syncthreads();
  }
  float* op = out + (size_t)(row0 + r) * NCLASS + cg;
#pragma unroll
  for (int j = 0; j < 5; j++) op[j] = acc[j];
}

extern "C" void kernel_launch(void* const* d_in, const int* in_sizes, int n_in,
                              void* d_out, int out_size, void* d_ws, size_t ws_size,
                              hipStream_t stream) {
  const float* x0 = (const float*)d_in[0];
  const float* x1 = (const float*)d_in[1];
  const int* ei = (const int*)d_in[2];
  const float* lw = (const float*)d_in[3];
  const float* lb = (const float*)d_in[4];
  const float* gw = (const float*)d_in[5];
  const float* ow = (const float*)d_in[6];
  const float* ob = (const float*)d_in[7];
  float* outp = (float*)d_out;

  float* h0 = (float*)d_ws;
  float* hb = h0 + (size_t)N_NODES * CHN;
  float* xb = hb + (size_t)N_NODES * CHN;
  int* cnt = (int*)(xb + (size_t)N_NODES * CHN);
  int* rowp = cnt + N_NODES;
  int* fill = rowp + N_NODES + 1;
  int* col = fill + N_NODES;

  const int* src = ei;
  const int* dst = ei + N_EDGES;

  hipMemsetAsync(cnt, 0, N_NODES * sizeof(int), stream);
  hist_kernel<<<(N_EDGES + 255) / 256, 256, 0, stream>>>(dst, cnt);
  scan_kernel<<<1, 1024, 0, stream>>>(cnt, rowp, fill);
  scatter_kernel<<<(N_EDGES + 255) / 256, 256, 0, stream>>>(src, dst, fill, col);

  dim3 lg((N_NODES + 63) / 64, 2);
  lin_kernel<<<lg, 256, 0, stream>>>(x0, x1, lw, lb, h0);

  const float* hin = h0;
  for (int l = 0; l < NLAYER; ++l) {
    float beta = logf(0.5f / (float)(l + 1) + 1.0f);
    agg_kernel<<<N_NODES / 4, 256, 0, stream>>>(hin, h0, rowp, col, xb);
    dim3 gg((N_NODES + 63) / 64, 2);
    layer_gemm_kernel<<<gg, 256, 0, stream>>>(xb, gw + (size_t)l * CHN * CHN, hb, beta);
    hin = hb;
  }
  out_kernel<<<N_NODES / 32, 256, 0, stream>>>(hb, ow, ob, outp);
}

// Round 2
// 1913.160 us; speedup vs baseline: 1.4160x; 1.4160x over previous
//
#include <hip/hip_runtime.h>
#include <cmath>

// LAGCNII round 1: bf16 MFMA GEMMs (fp32 accumulate, fp32 residual path),
// fp32 CSR gather aggregation. ws: h0|h|x fp32 (307MB) + CSR ints + bf16 W^T.

#define N_NODES 100000
#define N_EDGES 300000
#define DIN 256
#define CHN 256
#define DHID 128
#define NCLASS 40
#define NLAYER 8

typedef short bf16x8 __attribute__((ext_vector_type(8)));
typedef float f32x4 __attribute__((ext_vector_type(4)));

__device__ inline short f2bf(float f) {
  unsigned u = __float_as_uint(f);
  unsigned r = (u + 0x7FFFu + ((u >> 16) & 1u)) >> 16;
  return (short)r;
}

// ---------------- CSR build (by dst) ----------------
__global__ void hist_kernel(const int* __restrict__ dst, int* __restrict__ cnt) {
  int e = blockIdx.x * 256 + threadIdx.x;
  if (e < N_EDGES) atomicAdd(&cnt[dst[e]], 1);
}

__global__ __launch_bounds__(1024) void scan_kernel(const int* __restrict__ cnt,
                                                    int* __restrict__ rowp,
                                                    int* __restrict__ fill) {
  __shared__ int buf[1024];
  __shared__ int carry;
  int tid = threadIdx.x;
  if (tid == 0) carry = 0;
  __syncthreads();
  for (int base = 0; base < N_NODES; base += 1024) {
    int i = base + tid;
    int v = (i < N_NODES) ? cnt[i] : 0;
    buf[tid] = v;
    __syncthreads();
    for (int off = 1; off < 1024; off <<= 1) {
      int t = (tid >= off) ? buf[tid - off] : 0;
      __syncthreads();
      buf[tid] += t;
      __syncthreads();
    }
    int excl = buf[tid] - v;
    if (i < N_NODES) { int p = carry + excl; rowp[i] = p; fill[i] = p; }
    __syncthreads();
    if (tid == 1023) carry += buf[1023];
    __syncthreads();
  }
  if (tid == 0) rowp[N_NODES] = carry;
}

__global__ void scatter_kernel(const int* __restrict__ src, const int* __restrict__ dst,
                               int* __restrict__ fill, int* __restrict__ col) {
  int e = blockIdx.x * 256 + threadIdx.x;
  if (e < N_EDGES) {
    int p = atomicAdd(&fill[dst[e]], 1);
    col[p] = src[e];
  }
}

// ---------------- weight prep: bf16 transposed weights ----------------
// linT[v][n][k] (v<2,n<128,k<256), gcnT[l][n][k] (l<8,n<256,k<256)
__global__ void prep_w_kernel(const float* __restrict__ lw, const float* __restrict__ gw,
                              short* __restrict__ linT, short* __restrict__ gcnT) {
  int i = blockIdx.x * 256 + threadIdx.x;
  if (i < 2 * 128 * 256) {
    int v = i >> 15;
    int rem = i & 32767;
    int n = rem >> 8;
    int k = rem & 255;
    linT[i] = f2bf(lw[v * (DIN * DHID) + k * DHID + n]);
  }
  int j = i - 2 * 128 * 256;
  if (j >= 0 && j < 8 * 256 * 256) {
    int l = j >> 16;
    int rem = j & 65535;
    int n = rem >> 8;
    int k = rem & 255;
    gcnT[j] = f2bf(gw[l * (CHN * CHN) + k * CHN + n]);
  }
}

// ---------------- MFMA GEMM helpers ----------------
// Block: 256 thr (4 waves), tile 128 rows x 128 cols, BK=32, 16x16x32 bf16 MFMA.
// LDS rows padded to 40 shorts (80B) -> 2-way bank aliasing (free).

// lin: h0[:, v*128+n] = relu(Xv @ Wv + bv); A = Xv fp32 -> bf16 on the fly
__global__ __launch_bounds__(256) void lin_mfma_kernel(const float* __restrict__ x0,
                                                       const float* __restrict__ x1,
                                                       const short* __restrict__ linT,
                                                       const float* __restrict__ lb,
                                                       float* __restrict__ h0) {
  const int view = blockIdx.y;
  const float* __restrict__ X = view ? x1 : x0;
  const short* __restrict__ Wt = linT + view * (DHID * DIN);  // [n][k]
  const int row0 = blockIdx.x * 128;
  __shared__ short As[128 * 40];
  __shared__ short Bs[128 * 40];
  const int tid = threadIdx.x;
  const int lane = tid & 63, wave = tid >> 6;
  const int quad = lane >> 4, mrem = lane & 15;
  const int wrow = (wave & 1) * 64, wcol = (wave >> 1) * 64;

  f32x4 acc[4][4];
#pragma unroll
  for (int i = 0; i < 4; i++)
#pragma unroll
    for (int j = 0; j < 4; j++) acc[i][j] = (f32x4){0.f, 0.f, 0.f, 0.f};

  const int sr = tid >> 1;
  const int sk = (tid & 1) * 16;
  for (int k0 = 0; k0 < DIN; k0 += 32) {
    {
      int gr = row0 + sr;
      float v[16];
      if (gr < N_NODES) {
        const float* p = X + (size_t)gr * DIN + k0 + sk;
        *(float4*)(v + 0) = *(const float4*)(p + 0);
        *(float4*)(v + 4) = *(const float4*)(p + 4);
        *(float4*)(v + 8) = *(const float4*)(p + 8);
        *(float4*)(v + 12) = *(const float4*)(p + 12);
      } else {
#pragma unroll
        for (int i = 0; i < 16; i++) v[i] = 0.f;
      }
      short s[16];
#pragma unroll
      for (int i = 0; i < 16; i++) s[i] = f2bf(v[i]);
      *(bf16x8*)&As[sr * 40 + sk] = *(bf16x8*)(s);
      *(bf16x8*)&As[sr * 40 + sk + 8] = *(bf16x8*)(s + 8);
    }
    {
      const short* p = Wt + (size_t)sr * DIN + k0 + sk;
      bf16x8 b0 = *(const bf16x8*)p;
      bf16x8 b1 = *(const bf16x8*)(p + 8);
      *(bf16x8*)&Bs[sr * 40 + sk] = b0;
      *(bf16x8*)&Bs[sr * 40 + sk + 8] = b1;
    }
    __syncthreads();
    bf16x8 af[4], bfr[4];
#pragma unroll
    for (int i = 0; i < 4; i++) af[i] = *(const bf16x8*)&As[(wrow + i * 16 + mrem) * 40 + quad * 8];
#pragma unroll
    for (int j = 0; j < 4; j++) bfr[j] = *(const bf16x8*)&Bs[(wcol + j * 16 + mrem) * 40 + quad * 8];
#pragma unroll
    for (int i = 0; i < 4; i++)
#pragma unroll
      for (int j = 0; j < 4; j++)
        acc[i][j] = __builtin_amdgcn_mfma_f32_16x16x32_bf16(af[i], bfr[j], acc[i][j], 0, 0, 0);
    __syncthreads();
  }
#pragma unroll
  for (int i = 0; i < 4; i++) {
#pragma unroll
    for (int j = 0; j < 4; j++) {
      int lcol = wcol + j * 16 + mrem;  // 0..127
      float bb = lb[view * DHID + lcol];
#pragma unroll
      for (int r = 0; r < 4; r++) {
        int grow = row0 + wrow + i * 16 + quad * 4 + r;
        if (grow < N_NODES)
          h0[(size_t)grow * CHN + view * DHID + lcol] = fmaxf(acc[i][j][r] + bb, 0.f);
      }
    }
  }
}

// layer: h = relu((1-b)*x + b*(x @ W)); A = x fp32 -> bf16; residual x read fp32 (L2-warm)
__global__ __launch_bounds__(256) void layer_gemm_mfma(const float* __restrict__ x,
                                                       const short* __restrict__ Wt,  // [n][k]
                                                       float* __restrict__ h, float beta) {
  const int row0 = blockIdx.x * 128;
  const int col0 = blockIdx.y * 128;
  __shared__ short As[128 * 40];
  __shared__ short Bs[128 * 40];
  const int tid = threadIdx.x;
  const int lane = tid & 63, wave = tid >> 6;
  const int quad = lane >> 4, mrem = lane & 15;
  const int wrow = (wave & 1) * 64, wcol = (wave >> 1) * 64;

  f32x4 acc[4][4];
#pragma unroll
  for (int i = 0; i < 4; i++)
#pragma unroll
    for (int j = 0; j < 4; j++) acc[i][j] = (f32x4){0.f, 0.f, 0.f, 0.f};

  const int sr = tid >> 1;
  const int sk = (tid & 1) * 16;
  for (int k0 = 0; k0 < CHN; k0 += 32) {
    {
      int gr = row0 + sr;
      float v[16];
      if (gr < N_NODES) {
        const float* p = x + (size_t)gr * CHN + k0 + sk;
        *(float4*)(v + 0) = *(const float4*)(p + 0);
        *(float4*)(v + 4) = *(const float4*)(p + 4);
        *(float4*)(v + 8) = *(const float4*)(p + 8);
        *(float4*)(v + 12) = *(const float4*)(p + 12);
      } else {
#pragma unroll
        for (int i = 0; i < 16; i++) v[i] = 0.f;
      }
      short s[16];
#pragma unroll
      for (int i = 0; i < 16; i++) s[i] = f2bf(v[i]);
      *(bf16x8*)&As[sr * 40 + sk] = *(bf16x8*)(s);
      *(bf16x8*)&As[sr * 40 + sk + 8] = *(bf16x8*)(s + 8);
    }
    {
      const short* p = Wt + (size_t)(col0 + sr) * CHN + k0 + sk;
      bf16x8 b0 = *(const bf16x8*)p;
      bf16x8 b1 = *(const bf16x8*)(p + 8);
      *(bf16x8*)&Bs[sr * 40 + sk] = b0;
      *(bf16x8*)&Bs[sr * 40 + sk + 8] = b1;
    }
    __syncthreads();
    bf16x8 af[4], bfr[4];
#pragma unroll
    for (int i = 0; i < 4; i++) af[i] = *(const bf16x8*)&As[(wrow + i * 16 + mrem) * 40 + quad * 8];
#pragma unroll
    for (int j = 0; j < 4; j++) bfr[j] = *(const bf16x8*)&Bs[(wcol + j * 16 + mrem) * 40 + quad * 8];
#pragma unroll
    for (int i = 0; i < 4; i++)
#pragma unroll
      for (int j = 0; j < 4; j++)
        acc[i][j] = __builtin_amdgcn_mfma_f32_16x16x32_bf16(af[i], bfr[j], acc[i][j], 0, 0, 0);
    __syncthreads();
  }
  const float omb = 1.f - beta;
#pragma unroll
  for (int i = 0; i < 4; i++) {
#pragma unroll
    for (int j = 0; j < 4; j++) {
      int gcol = col0 + wcol + j * 16 + mrem;
#pragma unroll
      for (int r = 0; r < 4; r++) {
        int grow = row0 + wrow + i * 16 + quad * 4 + r;
        if (grow < N_NODES) {
          float xv = x[(size_t)grow * CHN + gcol];
          h[(size_t)grow * CHN + gcol] = fmaxf(omb * xv + beta * acc[i][j][r], 0.f);
        }
      }
    }
  }
}

// ---------------- aggregation: x = 0.9*sum_{e: dst=n} h[src_e] + 0.1*h0[n] ----------------
__global__ __launch_bounds__(256) void agg_kernel(const float* __restrict__ h,
                                                  const float* __restrict__ h0,
                                                  const int* __restrict__ rowp,
                                                  const int* __restrict__ col,
                                                  float* __restrict__ x) {
  int node = blockIdx.x * 4 + (threadIdx.x >> 6);
  int t = threadIdx.x & 63;
  int beg = rowp[node], end = rowp[node + 1];
  float4 acc = make_float4(0.f, 0.f, 0.f, 0.f);
  for (int e = beg; e < end; ++e) {
    int s = col[e];
    float4 v = *(const float4*)(h + (size_t)s * CHN + t * 4);
    acc.x += v.x; acc.y += v.y; acc.z += v.z; acc.w += v.w;
  }
  float4 r = *(const float4*)(h0 + (size_t)node * CHN + t * 4);
  float4 o;
  o.x = 0.9f * acc.x + 0.1f * r.x;
  o.y = 0.9f * acc.y + 0.1f * r.y;
  o.z = 0.9f * acc.z + 0.1f * r.z;
  o.w = 0.9f * acc.w + 0.1f * r.w;
  *(float4*)(x + (size_t)node * CHN + t * 4) = o;
}

// ---------------- out: out = h @ Wo + bo  (M=100000, K=256, N=40) ----------------
__global__ __launch_bounds__(256) void out_kernel(const float* __restrict__ h,
                                                  const float* __restrict__ W,
                                                  const float* __restrict__ b,
                                                  float* __restrict__ out) {
  __shared__ float xs[32][260];
  __shared__ float ws[64][40];
  const int row0 = blockIdx.x * 32;
  const int tid = threadIdx.x;
  for (int f = tid; f < 2048; f += 256) {
    int r = f >> 6;
    int c = (f & 63) * 4;
    *(float4*)&xs[r][c] = *(const float4*)(h + (size_t)(row0 + r) * CHN + c);
  }
  const int r = tid >> 3;
  const int cg = (tid & 7) * 5;
  float acc[5];
#pragma unroll
  for (int j = 0; j < 5; j++) acc[j] = b[cg + j];
  for (int k0 = 0; k0 < CHN; k0 += 64) {
    for (int i = tid; i < 64 * 40; i += 256) {
      int k = i / 40, c = i % 40;
      ws[k][c] = W[(size_t)(k0 + k) * NCLASS + c];
    }
    __syncthreads();
#pragma unroll 8
    for (int k = 0; k < 64; k++) {
      float xv = xs[r][k0 + k];
#pragma unroll
      for (int j = 0; j < 5; j++) acc[j] += xv * ws[k][cg + j];
    }
    __syncthreads();
  }
  float* op = out + (size_t)(row0 + r) * NCLASS + cg;
#pragma unroll
  for (int j = 0; j < 5; j++) op[j] = acc[j];
}

extern "C" void kernel_launch(void* const* d_in, const int* in_sizes, int n_in,
                              void* d_out, int out_size, void* d_ws, size_t ws_size,
                              hipStream_t stream) {
  const float* x0 = (const float*)d_in[0];
  const float* x1 = (const float*)d_in[1];
  const int* ei = (const int*)d_in[2];
  const float* lw = (const float*)d_in[3];
  const float* lb = (const float*)d_in[4];
  const float* gw = (const float*)d_in[5];
  const float* ow = (const float*)d_in[6];
  const float* ob = (const float*)d_in[7];
  float* outp = (float*)d_out;

  float* h0 = (float*)d_ws;
  float* hb = h0 + (size_t)N_NODES * CHN;
  float* xb = hb + (size_t)N_NODES * CHN;
  int* cnt = (int*)(xb + (size_t)N_NODES * CHN);
  int* rowp = cnt + N_NODES;
  int* fill = rowp + N_NODES + 1;
  int* col = fill + N_NODES;
  // pad to 16B alignment after 600,001 ints (+3)
  short* linT = (short*)(col + N_EDGES + 3);
  short* gcnT = linT + 2 * DHID * DIN;

  const int* src = ei;
  const int* dst = ei + N_EDGES;

  hipMemsetAsync(cnt, 0, N_NODES * sizeof(int), stream);
  hist_kernel<<<(N_EDGES + 255) / 256, 256, 0, stream>>>(dst, cnt);
  scan_kernel<<<1, 1024, 0, stream>>>(cnt, rowp, fill);
  scatter_kernel<<<(N_EDGES + 255) / 256, 256, 0, stream>>>(src, dst, fill, col);
  prep_w_kernel<<<(2 * 128 * 256 + 8 * 256 * 256 + 255) / 256, 256, 0, stream>>>(lw, gw, linT, gcnT);

  dim3 lg((N_NODES + 127) / 128, 2);
  lin_mfma_kernel<<<lg, 256, 0, stream>>>(x0, x1, linT, lb, h0);

  const float* hin = h0;
  for (int l = 0; l < NLAYER; ++l) {
    float beta = logf(0.5f / (float)(l + 1) + 1.0f);
    agg_kernel<<<N_NODES / 4, 256, 0, stream>>>(hin, h0, rowp, col, xb);
    dim3 gg((N_NODES + 127) / 128, 2);
    layer_gemm_mfma<<<gg, 256, 0, stream>>>(xb, gcnT + (size_t)l * CHN * CHN, hb, beta);
    hin = hb;
  }
  out_kernel<<<N_NODES / 32, 256, 0, stream>>>(hb, ow, ob, outp);
}

// Round 3
// 1315.959 us; speedup vs baseline: 2.0586x; 1.4538x over previous
//
#include <hip/hip_runtime.h>
#include <cmath>

// LAGCNII round 2: bf16 feature storage (h0/h/x), bf16 MFMA GEMMs (fp32 acc),
// multi-block CSR scan (was: 182us single-block scan), CSR gather aggregation.
// ws: h0|h|x bf16 (153.6MB) + bf16 W^T (1.2MB) + CSR ints (~2.4MB).

#define N_NODES 100000
#define N_EDGES 300000
#define DIN 256
#define CHN 256
#define DHID 128
#define NCLASS 40
#define NLAYER 8
#define SCAN_NB 98  // ceil(100000 / 1024)

typedef short bf16x8 __attribute__((ext_vector_type(8)));
typedef float f32x4 __attribute__((ext_vector_type(4)));

__device__ inline short f2bf(float f) {
  unsigned u = __float_as_uint(f);
  unsigned r = (u + 0x7FFFu + ((u >> 16) & 1u)) >> 16;
  return (short)r;
}
__device__ inline float bf2f(short s) {
  return __uint_as_float(((unsigned)(unsigned short)s) << 16);
}

// ---------------- CSR build (by dst) ----------------
__global__ void hist_kernel(const int* __restrict__ dst, int* __restrict__ cnt) {
  int e = blockIdx.x * 256 + threadIdx.x;
  if (e < N_EDGES) atomicAdd(&cnt[dst[e]], 1);
}

// per-block exclusive scan of 1024 values (256 thr x 4), block totals to bsums
__global__ __launch_bounds__(256) void bscan1(const int* __restrict__ cnt,
                                              int* __restrict__ rowp,
                                              int* __restrict__ bsums) {
  int tid = threadIdx.x;
  int base = blockIdx.x * 1024 + tid * 4;
  int v0 = 0, v1 = 0, v2 = 0, v3 = 0;
  if (base + 3 < N_NODES) {
    int4 v = *(const int4*)(cnt + base);
    v0 = v.x; v1 = v.y; v2 = v.z; v3 = v.w;
  } else {
    if (base + 0 < N_NODES) v0 = cnt[base + 0];
    if (base + 1 < N_NODES) v1 = cnt[base + 1];
    if (base + 2 < N_NODES) v2 = cnt[base + 2];
    if (base + 3 < N_NODES) v3 = cnt[base + 3];
  }
  int t = v0 + v1 + v2 + v3;
  int lane = tid & 63;
  int incl = t;
#pragma unroll
  for (int off = 1; off < 64; off <<= 1) {
    int x = __shfl_up(incl, off, 64);
    if (lane >= off) incl += x;
  }
  __shared__ int wsum[4];
  int wave = tid >> 6;
  if (lane == 63) wsum[wave] = incl;
  __syncthreads();
  int woff = 0;
  for (int w = 0; w < wave; w++) woff += wsum[w];
  int excl = woff + incl - t;
  int e0 = excl, e1 = e0 + v0, e2 = e1 + v1, e3 = e2 + v2;
  if (base + 0 < N_NODES) rowp[base + 0] = e0;
  if (base + 1 < N_NODES) rowp[base + 1] = e1;
  if (base + 2 < N_NODES) rowp[base + 2] = e2;
  if (base + 3 < N_NODES) rowp[base + 3] = e3;
  if (tid == 255) bsums[blockIdx.x] = woff + incl;
}

__global__ void bscan2(int* __restrict__ bsums, int* __restrict__ rowp) {
  if (threadIdx.x == 0 && blockIdx.x == 0) {
    int s = 0;
    for (int i = 0; i < SCAN_NB; i++) {
      int v = bsums[i];
      bsums[i] = s;
      s += v;
    }
    rowp[N_NODES] = s;
  }
}

__global__ __launch_bounds__(256) void bscan3(int* __restrict__ rowp,
                                              int* __restrict__ fill,
                                              const int* __restrict__ bsums) {
  int base = blockIdx.x * 1024 + threadIdx.x * 4;
  int off = bsums[blockIdx.x];
#pragma unroll
  for (int j = 0; j < 4; j++) {
    int i = base + j;
    if (i < N_NODES) {
      int p = rowp[i] + off;
      rowp[i] = p;
      fill[i] = p;
    }
  }
}

__global__ void scatter_kernel(const int* __restrict__ src, const int* __restrict__ dst,
                               int* __restrict__ fill, int* __restrict__ col) {
  int e = blockIdx.x * 256 + threadIdx.x;
  if (e < N_EDGES) {
    int p = atomicAdd(&fill[dst[e]], 1);
    col[p] = src[e];
  }
}

// ---------------- weight prep: bf16 transposed weights ----------------
__global__ void prep_w_kernel(const float* __restrict__ lw, const float* __restrict__ gw,
                              short* __restrict__ linT, short* __restrict__ gcnT) {
  int i = blockIdx.x * 256 + threadIdx.x;
  if (i < 2 * 128 * 256) {
    int v = i >> 15;
    int rem = i & 32767;
    int n = rem >> 8;
    int k = rem & 255;
    linT[i] = f2bf(lw[v * (DIN * DHID) + k * DHID + n]);
  }
  int j = i - 2 * 128 * 256;
  if (j >= 0 && j < 8 * 256 * 256) {
    int l = j >> 16;
    int rem = j & 65535;
    int n = rem >> 8;
    int k = rem & 255;
    gcnT[j] = f2bf(gw[l * (CHN * CHN) + k * CHN + n]);
  }
}

// ---------------- lin: h0[:, v*128+n] = relu(Xv @ Wv + bv), bf16 out ----------------
__global__ __launch_bounds__(256) void lin_mfma_kernel(const float* __restrict__ x0,
                                                       const float* __restrict__ x1,
                                                       const short* __restrict__ linT,
                                                       const float* __restrict__ lb,
                                                       short* __restrict__ h0) {
  const int view = blockIdx.y;
  const float* __restrict__ X = view ? x1 : x0;
  const short* __restrict__ Wt = linT + view * (DHID * DIN);  // [n][k]
  const int row0 = blockIdx.x * 128;
  __shared__ short As[128 * 40];
  __shared__ short Bs[128 * 40];
  const int tid = threadIdx.x;
  const int lane = tid & 63, wave = tid >> 6;
  const int quad = lane >> 4, mrem = lane & 15;
  const int wrow = (wave & 1) * 64, wcol = (wave >> 1) * 64;

  f32x4 acc[4][4];
#pragma unroll
  for (int i = 0; i < 4; i++)
#pragma unroll
    for (int j = 0; j < 4; j++) acc[i][j] = (f32x4){0.f, 0.f, 0.f, 0.f};

  const int sr = tid >> 1;
  const int sk = (tid & 1) * 16;
  for (int k0 = 0; k0 < DIN; k0 += 32) {
    {
      int gr = row0 + sr;
      float v[16];
      if (gr < N_NODES) {
        const float* p = X + (size_t)gr * DIN + k0 + sk;
        *(float4*)(v + 0) = *(const float4*)(p + 0);
        *(float4*)(v + 4) = *(const float4*)(p + 4);
        *(float4*)(v + 8) = *(const float4*)(p + 8);
        *(float4*)(v + 12) = *(const float4*)(p + 12);
      } else {
#pragma unroll
        for (int i = 0; i < 16; i++) v[i] = 0.f;
      }
      short s[16];
#pragma unroll
      for (int i = 0; i < 16; i++) s[i] = f2bf(v[i]);
      *(bf16x8*)&As[sr * 40 + sk] = *(bf16x8*)(s);
      *(bf16x8*)&As[sr * 40 + sk + 8] = *(bf16x8*)(s + 8);
    }
    {
      const short* p = Wt + (size_t)sr * DIN + k0 + sk;
      bf16x8 b0 = *(const bf16x8*)p;
      bf16x8 b1 = *(const bf16x8*)(p + 8);
      *(bf16x8*)&Bs[sr * 40 + sk] = b0;
      *(bf16x8*)&Bs[sr * 40 + sk + 8] = b1;
    }
    __syncthreads();
    bf16x8 af[4], bfr[4];
#pragma unroll
    for (int i = 0; i < 4; i++) af[i] = *(const bf16x8*)&As[(wrow + i * 16 + mrem) * 40 + quad * 8];
#pragma unroll
    for (int j = 0; j < 4; j++) bfr[j] = *(const bf16x8*)&Bs[(wcol + j * 16 + mrem) * 40 + quad * 8];
#pragma unroll
    for (int i = 0; i < 4; i++)
#pragma unroll
      for (int j = 0; j < 4; j++)
        acc[i][j] = __builtin_amdgcn_mfma_f32_16x16x32_bf16(af[i], bfr[j], acc[i][j], 0, 0, 0);
    __syncthreads();
  }
#pragma unroll
  for (int i = 0; i < 4; i++) {
#pragma unroll
    for (int j = 0; j < 4; j++) {
      int lcol = wcol + j * 16 + mrem;
      float bb = lb[view * DHID + lcol];
#pragma unroll
      for (int r = 0; r < 4; r++) {
        int grow = row0 + wrow + i * 16 + quad * 4 + r;
        if (grow < N_NODES)
          h0[(size_t)grow * CHN + view * DHID + lcol] = f2bf(fmaxf(acc[i][j][r] + bb, 0.f));
      }
    }
  }
}

// ---------------- layer GEMM: h = relu((1-b)*x + b*(x@W)), all bf16 I/O ----------------
__global__ __launch_bounds__(256) void layer_gemm_mfma(const short* __restrict__ x,
                                                       const short* __restrict__ Wt,  // [n][k]
                                                       short* __restrict__ h, float beta) {
  const int row0 = blockIdx.x * 128;
  const int col0 = blockIdx.y * 128;
  __shared__ short As[128 * 40];
  __shared__ short Bs[128 * 40];
  const int tid = threadIdx.x;
  const int lane = tid & 63, wave = tid >> 6;
  const int quad = lane >> 4, mrem = lane & 15;
  const int wrow = (wave & 1) * 64, wcol = (wave >> 1) * 64;

  f32x4 acc[4][4];
#pragma unroll
  for (int i = 0; i < 4; i++)
#pragma unroll
    for (int j = 0; j < 4; j++) acc[i][j] = (f32x4){0.f, 0.f, 0.f, 0.f};

  const int sr = tid >> 1;
  const int sk = (tid & 1) * 16;
  for (int k0 = 0; k0 < CHN; k0 += 32) {
    {
      int gr = row0 + sr;
      bf16x8 a0 = (bf16x8)(short)0, a1 = (bf16x8)(short)0;
      if (gr < N_NODES) {
        const short* p = x + (size_t)gr * CHN + k0 + sk;
        a0 = *(const bf16x8*)p;
        a1 = *(const bf16x8*)(p + 8);
      }
      *(bf16x8*)&As[sr * 40 + sk] = a0;
      *(bf16x8*)&As[sr * 40 + sk + 8] = a1;
    }
    {
      const short* p = Wt + (size_t)(col0 + sr) * CHN + k0 + sk;
      bf16x8 b0 = *(const bf16x8*)p;
      bf16x8 b1 = *(const bf16x8*)(p + 8);
      *(bf16x8*)&Bs[sr * 40 + sk] = b0;
      *(bf16x8*)&Bs[sr * 40 + sk + 8] = b1;
    }
    __syncthreads();
    bf16x8 af[4], bfr[4];
#pragma unroll
    for (int i = 0; i < 4; i++) af[i] = *(const bf16x8*)&As[(wrow + i * 16 + mrem) * 40 + quad * 8];
#pragma unroll
    for (int j = 0; j < 4; j++) bfr[j] = *(const bf16x8*)&Bs[(wcol + j * 16 + mrem) * 40 + quad * 8];
#pragma unroll
    for (int i = 0; i < 4; i++)
#pragma unroll
      for (int j = 0; j < 4; j++)
        acc[i][j] = __builtin_amdgcn_mfma_f32_16x16x32_bf16(af[i], bfr[j], acc[i][j], 0, 0, 0);
    __syncthreads();
  }
  const float omb = 1.f - beta;
#pragma unroll
  for (int i = 0; i < 4; i++) {
#pragma unroll
    for (int j = 0; j < 4; j++) {
      int gcol = col0 + wcol + j * 16 + mrem;
#pragma unroll
      for (int r = 0; r < 4; r++) {
        int grow = row0 + wrow + i * 16 + quad * 4 + r;
        if (grow < N_NODES) {
          float xv = bf2f(x[(size_t)grow * CHN + gcol]);
          h[(size_t)grow * CHN + gcol] = f2bf(fmaxf(omb * xv + beta * acc[i][j][r], 0.f));
        }
      }
    }
  }
}

// ---------------- aggregation: x = 0.9*sum_{e: dst=n} h[src_e] + 0.1*h0[n] ----------------
__global__ __launch_bounds__(256) void agg_kernel(const short* __restrict__ h,
                                                  const short* __restrict__ h0,
                                                  const int* __restrict__ rowp,
                                                  const int* __restrict__ col,
                                                  short* __restrict__ x) {
  int node = blockIdx.x * 4 + (threadIdx.x >> 6);
  int t = threadIdx.x & 63;
  int beg = rowp[node], end = rowp[node + 1];
  float a0 = 0.f, a1 = 0.f, a2 = 0.f, a3 = 0.f;
  for (int e = beg; e < end; ++e) {
    int s = col[e];
    short4 v = *(const short4*)(h + (size_t)s * CHN + t * 4);
    a0 += bf2f(v.x); a1 += bf2f(v.y); a2 += bf2f(v.z); a3 += bf2f(v.w);
  }
  short4 r = *(const short4*)(h0 + (size_t)node * CHN + t * 4);
  short4 o;
  o.x = f2bf(0.9f * a0 + 0.1f * bf2f(r.x));
  o.y = f2bf(0.9f * a1 + 0.1f * bf2f(r.y));
  o.z = f2bf(0.9f * a2 + 0.1f * bf2f(r.z));
  o.w = f2bf(0.9f * a3 + 0.1f * bf2f(r.w));
  *(short4*)(x + (size_t)node * CHN + t * 4) = o;
}

// ---------------- out: out = h @ Wo + bo  (M=100000, K=256, N=40) ----------------
__global__ __launch_bounds__(256) void out_kernel(const short* __restrict__ h,
                                                  const float* __restrict__ W,
                                                  const float* __restrict__ b,
                                                  float* __restrict__ out) {
  __shared__ float xs[32][260];
  __shared__ float ws[64][40];
  const int row0 = blockIdx.x * 32;
  const int tid = threadIdx.x;
  for (int f = tid; f < 1024; f += 256) {
    int r = f >> 5;
    int c = (f & 31) * 8;
    bf16x8 v = *(const bf16x8*)(h + (size_t)(row0 + r) * CHN + c);
    float t0[8];
#pragma unroll
    for (int q = 0; q < 8; q++) t0[q] = bf2f(v[q]);
    *(float4*)&xs[r][c] = *(float4*)(t0);
    *(float4*)&xs[r][c + 4] = *(float4*)(t0 + 4);
  }
  const int r = tid >> 3;
  const int cg = (tid & 7) * 5;
  float acc[5];
#pragma unroll
  for (int j = 0; j < 5; j++) acc[j] = b[cg + j];
  for (int k0 = 0; k0 < CHN; k0 += 64) {
    for (int i = tid; i < 64 * 40; i += 256) {
      int k = i / 40, c = i % 40;
      ws[k][c] = W[(size_t)(k0 + k) * NCLASS + c];
    }
    __syncthreads();
#pragma unroll 8
    for (int k = 0; k < 64; k++) {
      float xv = xs[r][k0 + k];
#pragma unroll
      for (int j = 0; j < 5; j++) acc[j] += xv * ws[k][cg + j];
    }
    __syncthreads();
  }
  float* op = out + (size_t)(row0 + r) * NCLASS + cg;
#pragma unroll
  for (int j = 0; j < 5; j++) op[j] = acc[j];
}

extern "C" void kernel_launch(void* const* d_in, const int* in_sizes, int n_in,
                              void* d_out, int out_size, void* d_ws, size_t ws_size,
                              hipStream_t stream) {
  const float* x0 = (const float*)d_in[0];
  const float* x1 = (const float*)d_in[1];
  const int* ei = (const int*)d_in[2];
  const float* lw = (const float*)d_in[3];
  const float* lb = (const float*)d_in[4];
  const float* gw = (const float*)d_in[5];
  const float* ow = (const float*)d_in[6];
  const float* ob = (const float*)d_in[7];
  float* outp = (float*)d_out;

  const size_t NC = (size_t)N_NODES * CHN;
  short* h0 = (short*)d_ws;
  short* hb = h0 + NC;
  short* xb = hb + NC;
  short* linT = xb + NC;                    // 153.6MB offset, 16B aligned
  short* gcnT = linT + 2 * DHID * DIN;      // +128KB
  int* cnt = (int*)(gcnT + 8 * CHN * CHN);  // +1MB
  int* rowp = cnt + N_NODES;
  int* fill = rowp + N_NODES + 1;
  int* col = fill + N_NODES;
  int* bsums = col + N_EDGES;

  const int* src = ei;
  const int* dst = ei + N_EDGES;

  hipMemsetAsync(cnt, 0, N_NODES * sizeof(int), stream);
  hist_kernel<<<(N_EDGES + 255) / 256, 256, 0, stream>>>(dst, cnt);
  bscan1<<<SCAN_NB, 256, 0, stream>>>(cnt, rowp, bsums);
  bscan2<<<1, 64, 0, stream>>>(bsums, rowp);
  bscan3<<<SCAN_NB, 256, 0, stream>>>(rowp, fill, bsums);
  scatter_kernel<<<(N_EDGES + 255) / 256, 256, 0, stream>>>(src, dst, fill, col);
  prep_w_kernel<<<(2 * 128 * 256 + 8 * 256 * 256 + 255) / 256, 256, 0, stream>>>(lw, gw, linT, gcnT);

  dim3 lg((N_NODES + 127) / 128, 2);
  lin_mfma_kernel<<<lg, 256, 0, stream>>>(x0, x1, linT, lb, h0);

  const short* hin = h0;
  for (int l = 0; l < NLAYER; ++l) {
    float beta = logf(0.5f / (float)(l + 1) + 1.0f);
    agg_kernel<<<N_NODES / 4, 256, 0, stream>>>(hin, h0, rowp, col, xb);
    dim3 gg((N_NODES + 127) / 128, 2);
    layer_gemm_mfma<<<gg, 256, 0, stream>>>(xb, gcnT + (size_t)l * CHN * CHN, hb, beta);
    hin = hb;
  }
  out_kernel<<<N_NODES / 32, 256, 0, stream>>>(hb, ow, ob, outp);
}